// Round 2
// baseline (3056.006 us; speedup 1.0000x reference)
//
#include <hip/hip_runtime.h>
#include <cstdint>
#include <cstddef>

#define TLEN 500
#define BATCH 128
#define NDIM 300
#define EDIM 128
#define CDIM 128
#define UDIM 64
#define FDIM 4
#define G3 384           // 3*E == 3*C
#define CLIPV 5.0f

// ---------------------------------------------------------------------------
// dot of a 128-float register row with h (broadcast via v_readlane).
// hv0/hv1 must be loaded with ALL 64 LANES OF THE WAVE ACTIVE (readlane reads
// lane registers regardless of exec, so masked-off lanes would contribute
// stale garbage). Callers must only invoke this from wave-uniform control flow.
// ---------------------------------------------------------------------------
static __device__ __forceinline__ float dot128_rl(const float* __restrict__ w,
                                                  float hv0, float hv1) {
    const int h0 = __float_as_int(hv0);
    const int h1 = __float_as_int(hv1);
    float a0 = 0.f, a1 = 0.f, a2 = 0.f, a3 = 0.f;
#pragma unroll
    for (int j = 0; j < 64; j += 4) {
        a0 = fmaf(w[j + 0], __int_as_float(__builtin_amdgcn_readlane(h0, j + 0)), a0);
        a1 = fmaf(w[j + 1], __int_as_float(__builtin_amdgcn_readlane(h0, j + 1)), a1);
        a2 = fmaf(w[j + 2], __int_as_float(__builtin_amdgcn_readlane(h0, j + 2)), a2);
        a3 = fmaf(w[j + 3], __int_as_float(__builtin_amdgcn_readlane(h0, j + 3)), a3);
    }
#pragma unroll
    for (int j = 0; j < 64; j += 4) {
        a0 = fmaf(w[64 + j + 0], __int_as_float(__builtin_amdgcn_readlane(h1, j + 0)), a0);
        a1 = fmaf(w[64 + j + 1], __int_as_float(__builtin_amdgcn_readlane(h1, j + 1)), a1);
        a2 = fmaf(w[64 + j + 2], __int_as_float(__builtin_amdgcn_readlane(h1, j + 2)), a2);
        a3 = fmaf(w[64 + j + 3], __int_as_float(__builtin_amdgcn_readlane(h1, j + 3)), a3);
    }
    return (a0 + a1) + (a2 + a3);
}

static __device__ __forceinline__ float sigm(float x) {
    return 1.0f / (1.0f + expf(-x));
}

// ---------------------------------------------------------------------------
// Fused GEMM:  C[m,n] = bias[n] + sum_k A1[m,k]*W[n, wofs1+k]  (K1 terms)
//                               + sum_k A2[m,k]*W[n, wofs2+k]  (K2 terms, A2 may be null)
// A row-major [M,lda], W row-major [N,ldw]. Tile 128x128, BK=8, 256 thr, 8x8 micro.
// All K's and wofs are multiples of 4 and all row pitches are 16B-aligned.
// ---------------------------------------------------------------------------
__global__ __launch_bounds__(256) void gemm_fused_kernel(
    const float* __restrict__ A1, int lda1, int K1, int wofs1,
    const float* __restrict__ A2, int lda2, int K2, int wofs2,
    const float* __restrict__ W, int ldw,
    const float* __restrict__ bias,
    float* __restrict__ C, int ldc)
{
    __shared__ float As[8][128];
    __shared__ float Bs[8][128];
    const int tid = threadIdx.x;
    const int m0 = blockIdx.x * 128;
    const int n0 = blockIdx.y * 128;
    const int lr = tid >> 1;           // 0..127 : tile row loaded by this thread
    const int lc = (tid & 1) << 2;     // 0 or 4 : k-offset loaded
    const int ty = tid >> 4;           // 0..15
    const int tx = tid & 15;           // 0..15

    float acc[8][8];
#pragma unroll
    for (int i = 0; i < 8; ++i)
#pragma unroll
        for (int j = 0; j < 8; ++j) acc[i][j] = 0.f;

#pragma unroll 1
    for (int phase = 0; phase < 2; ++phase) {
        const float* __restrict__ A = phase ? A2 : A1;
        if (A == nullptr) continue;
        const int lda  = phase ? lda2  : lda1;
        const int K    = phase ? K2    : K1;
        const int wofs = phase ? wofs2 : wofs1;
        for (int k0 = 0; k0 < K; k0 += 8) {
            const int k = k0 + lc;
            float4 av = make_float4(0.f, 0.f, 0.f, 0.f);
            float4 bv = make_float4(0.f, 0.f, 0.f, 0.f);
            if (k < K) {
                av = *(const float4*)(A + (size_t)(m0 + lr) * lda + k);
                bv = *(const float4*)(W + (size_t)(n0 + lr) * ldw + wofs + k);
            }
            __syncthreads();
            As[lc + 0][lr] = av.x; As[lc + 1][lr] = av.y;
            As[lc + 2][lr] = av.z; As[lc + 3][lr] = av.w;
            Bs[lc + 0][lr] = bv.x; Bs[lc + 1][lr] = bv.y;
            Bs[lc + 2][lr] = bv.z; Bs[lc + 3][lr] = bv.w;
            __syncthreads();
#pragma unroll
            for (int kk = 0; kk < 8; ++kk) {
                float a[8], bb[8];
#pragma unroll
                for (int i = 0; i < 4; ++i) {
                    a[i]     = As[kk][ty * 4 + i];
                    a[4 + i] = As[kk][64 + ty * 4 + i];
                }
#pragma unroll
                for (int j = 0; j < 4; ++j) {
                    bb[j]     = Bs[kk][tx * 4 + j];
                    bb[4 + j] = Bs[kk][64 + tx * 4 + j];
                }
#pragma unroll
                for (int i = 0; i < 8; ++i)
#pragma unroll
                    for (int j = 0; j < 8; ++j)
                        acc[i][j] = fmaf(a[i], bb[j], acc[i][j]);
            }
        }
    }
#pragma unroll
    for (int i = 0; i < 8; ++i) {
        const int rr = m0 + ((i < 4) ? (ty * 4 + i) : (64 + ty * 4 + (i - 4)));
#pragma unroll
        for (int j = 0; j < 8; ++j) {
            const int cc = n0 + ((j < 4) ? (tx * 4 + j) : (64 + tx * 4 + (j - 4)));
            C[(size_t)rr * ldc + cc] = acc[i][j] + bias[cc];
        }
    }
}

// ---------------------------------------------------------------------------
// Bidirectional encoder GRU scans. 256 WGs (0..127 fwd batch b, 128..255 bwd),
// 384 threads: thread r owns Whh row r in VGPRs. Per step: readlane matvec,
// gate math on threads 0..127, clipped copy to g. State h is NOT clipped.
// Backward WG iterates t = 499..0 reading xp_b row t (xp_b computed UNREVERSED
// as x @ Whh_b.T, so row t == reference's xp_b scan step s = T-1-t) and writes
// g[t, :, 128:256] (== gb[::-1]).
// ---------------------------------------------------------------------------
__global__ __launch_bounds__(384) void enc_scan_kernel(
    const float* __restrict__ xp,      // xp_f, with xp_b at +TLEN*BATCH*G3
    const float* __restrict__ Whh_f, const float* __restrict__ bhh_f,
    const float* __restrict__ Whh_b, const float* __restrict__ bhh_b,
    const float* __restrict__ enc_init,
    float* __restrict__ g)             // [T*B, 2*EDIM]
{
    const int wg  = blockIdx.x;
    const int dir = wg >> 7;
    const int b   = wg & 127;
    const int tid = threadIdx.x;
    const int lane = tid & 63;
    const float* __restrict__ Whh = dir ? Whh_b : Whh_f;
    const float* __restrict__ bhh = dir ? bhh_b : bhh_f;
    const float* __restrict__ xpd = xp + (size_t)dir * ((size_t)TLEN * BATCH * G3);

    __shared__ float h_lds[EDIM];
    __shared__ float hh_lds[G3];

    float w[128];
    {
        const float4* src = (const float4*)(Whh + (size_t)tid * 128);
#pragma unroll
        for (int i = 0; i < 32; ++i) {
            float4 v = src[i];
            w[4 * i] = v.x; w[4 * i + 1] = v.y; w[4 * i + 2] = v.z; w[4 * i + 3] = v.w;
        }
    }
    const float brow = bhh[tid];
    if (tid < EDIM) h_lds[tid] = enc_init[dir * EDIM + tid];
    __syncthreads();

    for (int s = 0; s < TLEN; ++s) {
        const int t = dir ? (TLEN - 1 - s) : s;
        const size_t row = (size_t)t * BATCH + b;
        // unconditional loads + unconditional dot: readlane sees all lanes live
        const float hv0 = h_lds[lane];
        const float hv1 = h_lds[64 + lane];
        const float hh = dot128_rl(w, hv0, hv1) + brow;
        hh_lds[tid] = hh;
        __syncthreads();
        if (tid < EDIM) {   // waves 0,1 fully active (wave-uniform branch)
            const float* xrow = xpd + row * G3;
            const float xr = xrow[tid], xz = xrow[EDIM + tid], xn = xrow[2 * EDIM + tid];
            const float hr = hh_lds[tid], hz = hh_lds[EDIM + tid], hn = hh_lds[2 * EDIM + tid];
            const float r = sigm(xr + hr);
            const float z = sigm(xz + hz);
            const float n = tanhf(xn + r * hn);
            const float hold = h_lds[tid];
            const float hnew = (1.f - z) * n + z * hold;
            h_lds[tid] = hnew;
            g[row * (2 * EDIM) + dir * EDIM + tid] = fminf(fmaxf(hnew, -CLIPV), CLIPV);
        }
        __syncthreads();
    }
}

// ---------------------------------------------------------------------------
// Controller GRU + latent sample + spike + AR1 calcium. 128 WGs (one per batch),
// 512 threads:
//   tid 0..383  : ctrl_Whh row (128 VGPRs) ; tid 0..319 also W_spk row (clamped)
//   tid 384..511: W_mu row (tid-384 < 64) or W_lv row  (128 VGPRs)
// ALL branches containing readlane are wave-uniform:
//   waves 0..5  = tid<384  (phase A)
//   waves 6..7  = tid>=384 (phase B)
//   waves 0..4  = tid<320  (phase C; W_spk row index clamped to 299, store
//                 guarded by tid<300 — the only non-uniform part is the store)
// ---------------------------------------------------------------------------
__global__ __launch_bounds__(512) void ctrl_scan_kernel(
    const float* __restrict__ cp,       // [T*B, 384]
    const float* __restrict__ factors,  // [T*B, 4]
    const float* __restrict__ eps,      // [T*B, 64]
    const float* __restrict__ Whh, const float* __restrict__ bhh,
    const float* __restrict__ ctrl_init,
    const float* __restrict__ W_mu, const float* __restrict__ b_mu,
    const float* __restrict__ W_lv, const float* __restrict__ b_lv,
    const float* __restrict__ W_spk, const float* __restrict__ b_spk,
    const float* __restrict__ gain_p, const float* __restrict__ bias_p_p,
    const float* __restrict__ logtau_p,
    float* __restrict__ out)            // [T*B, 300]
{
    const int b   = blockIdx.x;
    const int tid = threadIdx.x;
    const int lane = tid & 63;

    __shared__ float h_lds[CDIM];
    __shared__ float hh_lds[G3];
    __shared__ float lv_lds[UDIM];
    __shared__ float gen_lds[UDIM + FDIM];

    float wbig[128];
    float wspk[68];
    float bias_row = 0.f, bspk_r = 0.f;

    if (tid < G3) {
        const float4* src = (const float4*)(Whh + (size_t)tid * 128);
#pragma unroll
        for (int i = 0; i < 32; ++i) {
            float4 v = src[i];
            wbig[4 * i] = v.x; wbig[4 * i + 1] = v.y; wbig[4 * i + 2] = v.z; wbig[4 * i + 3] = v.w;
        }
        bias_row = bhh[tid];
    } else {
        const int mrow = tid - G3;
        const float* Wsrc = (mrow < UDIM) ? (W_mu + (size_t)mrow * 128)
                                          : (W_lv + (size_t)(mrow - UDIM) * 128);
        const float4* src = (const float4*)Wsrc;
#pragma unroll
        for (int i = 0; i < 32; ++i) {
            float4 v = src[i];
            wbig[4 * i] = v.x; wbig[4 * i + 1] = v.y; wbig[4 * i + 2] = v.z; wbig[4 * i + 3] = v.w;
        }
        bias_row = (mrow < UDIM) ? b_mu[mrow] : b_lv[mrow - UDIM];
    }
    if (tid < 320) {                    // wave-uniform: waves 0..4
        const int srow = (tid < NDIM) ? tid : (NDIM - 1);   // clamp pad threads
        const float4* src = (const float4*)(W_spk + (size_t)srow * 68);
#pragma unroll
        for (int i = 0; i < 17; ++i) {
            float4 v = src[i];
            wspk[4 * i] = v.x; wspk[4 * i + 1] = v.y; wspk[4 * i + 2] = v.z; wspk[4 * i + 3] = v.w;
        }
        bspk_r = b_spk[srow];
    }
    const float gain  = gain_p[0];
    const float biasp = bias_p_p[0];
    const float decay = 1.0f - expf(-logtau_p[0]);
    if (tid < CDIM) h_lds[tid] = ctrl_init[tid];
    float cal = 0.0f;
    __syncthreads();

    float hv0 = h_lds[lane];
    float hv1 = h_lds[64 + lane];

    for (int t = 0; t < TLEN; ++t) {
        const size_t row = (size_t)t * BATCH + b;
        // ---- phase A: recurrent matvec hh = Whh @ h + bhh (waves 0..5) ----
        if (tid < G3) hh_lds[tid] = dot128_rl(wbig, hv0, hv1) + bias_row;
        __syncthreads();  // A
        // ---- gates (threads 0..127, waves 0,1), clip state ----
        if (tid < CDIM) {
            const float* cpr = cp + row * G3;
            const float xr = cpr[tid], xz = cpr[CDIM + tid], xn = cpr[2 * CDIM + tid];
            const float hr = hh_lds[tid], hz = hh_lds[CDIM + tid], hn = hh_lds[2 * CDIM + tid];
            const float r = sigm(xr + hr);
            const float z = sigm(xz + hz);
            const float n = tanhf(xn + r * hn);
            const float hold = h_lds[tid];
            float hnew = (1.f - z) * n + z * hold;
            hnew = fminf(fmaxf(hnew, -CLIPV), CLIPV);
            h_lds[tid] = hnew;
        }
        if (tid >= 448 && tid < 448 + FDIM) {
            gen_lds[UDIM + (tid - 448)] = factors[row * FDIM + (tid - 448)];
        }
        __syncthreads();  // B
        hv0 = h_lds[lane];         // reload new h (used by mu/lv now, Whh next step)
        hv1 = h_lds[64 + lane];
        // ---- phase B: mu / lv (threads 384..511, waves 6,7) ----
        float muv = 0.f;
        if (tid >= G3) {
            const float v = dot128_rl(wbig, hv0, hv1) + bias_row;
            const int mrow = tid - G3;
            if (mrow < UDIM) muv = v; else lv_lds[mrow - UDIM] = v;
        }
        __syncthreads();  // C
        if (tid >= G3 && tid < G3 + UDIM) {
            const int j = tid - G3;
            const float e = eps[row * UDIM + j];
            gen_lds[j] = muv + expf(0.5f * lv_lds[j]) * e;
        }
        __syncthreads();  // D
        // ---- phase C: spike + calcium (waves 0..4, WAVE-UNIFORM branch) ----
        if (tid < 320) {
            const float gval = gen_lds[lane];   // all 64 lanes of waves 0..4 live
            const int gvi = __float_as_int(gval);
            float a0 = 0.f, a1 = 0.f, a2 = 0.f, a3 = 0.f;
#pragma unroll
            for (int j = 0; j < 64; j += 4) {
                a0 = fmaf(wspk[j + 0], __int_as_float(__builtin_amdgcn_readlane(gvi, j + 0)), a0);
                a1 = fmaf(wspk[j + 1], __int_as_float(__builtin_amdgcn_readlane(gvi, j + 1)), a1);
                a2 = fmaf(wspk[j + 2], __int_as_float(__builtin_amdgcn_readlane(gvi, j + 2)), a2);
                a3 = fmaf(wspk[j + 3], __int_as_float(__builtin_amdgcn_readlane(gvi, j + 3)), a3);
            }
            float acc = (a0 + a1) + (a2 + a3);
#pragma unroll
            for (int q = 0; q < FDIM; ++q) acc = fmaf(wspk[64 + q], gen_lds[UDIM + q], acc);
            acc += bspk_r;
            const float sp = fmaxf(expf(acc) - 1.0f, 0.0f);
            cal = cal * decay + gain * sp + biasp;
            if (tid < NDIM) out[row * NDIM + tid] = cal;  // only the store diverges
        }
        __syncthreads();  // E (protect gen_lds/lv_lds for next iter)
    }
}

// ---------------------------------------------------------------------------
extern "C" void kernel_launch(void* const* d_in, const int* in_sizes, int n_in,
                              void* d_out, int out_size, void* d_ws, size_t ws_size,
                              hipStream_t stream) {
    const float* x         = (const float*)d_in[0];
    const float* factors   = (const float*)d_in[1];
    const float* eps       = (const float*)d_in[2];
    const float* enc_Wih_f = (const float*)d_in[3];
    const float* enc_Whh_f = (const float*)d_in[4];
    const float* enc_bih_f = (const float*)d_in[5];
    const float* enc_bhh_f = (const float*)d_in[6];
    const float* enc_Wih_b = (const float*)d_in[7];
    const float* enc_Whh_b = (const float*)d_in[8];
    const float* enc_bih_b = (const float*)d_in[9];
    const float* enc_bhh_b = (const float*)d_in[10];
    const float* enc_init  = (const float*)d_in[11];
    const float* ctrl_Wih  = (const float*)d_in[12];
    const float* ctrl_Whh  = (const float*)d_in[13];
    const float* ctrl_bih  = (const float*)d_in[14];
    const float* ctrl_bhh  = (const float*)d_in[15];
    const float* ctrl_init = (const float*)d_in[16];
    const float* W_mu      = (const float*)d_in[17];
    const float* b_mu      = (const float*)d_in[18];
    const float* W_lv      = (const float*)d_in[19];
    const float* b_lv      = (const float*)d_in[20];
    const float* W_spk     = (const float*)d_in[21];
    const float* b_spk     = (const float*)d_in[22];
    const float* gain      = (const float*)d_in[23];
    const float* bias_p    = (const float*)d_in[24];
    const float* logtau    = (const float*)d_in[25];
    float* out = (float*)d_out;
    float* ws  = (float*)d_ws;

    const size_t PROJ = (size_t)TLEN * BATCH * G3;   // 24,576,000 floats
    float* xpf = ws;
    float* xpb = ws + PROJ;
    float* g   = ws + 2 * PROJ;                      // [T*B, 256]
    float* cp  = ws;                                 // reuse xpf region after encoder

    dim3 ggrid(500, 3);  // M/128 = 64000/128, N/128 = 384/128

    // xp_f = x @ enc_Wih_f.T + bih_f ; xp_b = x @ enc_Wih_b.T + bih_b
    gemm_fused_kernel<<<ggrid, 256, 0, stream>>>(x, NDIM, NDIM, 0,
                                                 nullptr, 0, 0, 0,
                                                 enc_Wih_f, NDIM, enc_bih_f, xpf, G3);
    gemm_fused_kernel<<<ggrid, 256, 0, stream>>>(x, NDIM, NDIM, 0,
                                                 nullptr, 0, 0, 0,
                                                 enc_Wih_b, NDIM, enc_bih_b, xpb, G3);
    // bidirectional encoder scans -> g (clipped)
    enc_scan_kernel<<<256, 384, 0, stream>>>(xpf, enc_Whh_f, enc_bhh_f,
                                             enc_Whh_b, enc_bhh_b, enc_init, g);
    // cp = g @ ctrl_Wih[:, :256].T + x @ ctrl_Wih[:, 256:].T + ctrl_bih
    gemm_fused_kernel<<<ggrid, 256, 0, stream>>>(g, 2 * EDIM, 2 * EDIM, 0,
                                                 x, NDIM, NDIM, 2 * EDIM,
                                                 ctrl_Wih, 2 * EDIM + NDIM, ctrl_bih, cp, G3);
    // controller scan + latent + spike + calcium -> out
    ctrl_scan_kernel<<<128, 512, 0, stream>>>(cp, factors, eps,
                                              ctrl_Whh, ctrl_bhh, ctrl_init,
                                              W_mu, b_mu, W_lv, b_lv,
                                              W_spk, b_spk,
                                              gain, bias_p, logtau, out);
}

// Round 3
// 2597.627 us; speedup vs baseline: 1.1765x; 1.1765x over previous
//
#include <hip/hip_runtime.h>
#include <cstdint>
#include <cstddef>

#define TLEN 500
#define BATCH 128
#define NDIM 300
#define EDIM 128
#define CDIM 128
#define UDIM 64
#define FDIM 4
#define G3 384           // 3*E == 3*C
#define CLIPV 5.0f

// ---------------------------------------------------------------------------
// dot of a 128-float register row with h (broadcast via v_readlane).
// hv0/hv1 must be loaded with ALL 64 LANES OF THE WAVE ACTIVE (readlane reads
// lane registers regardless of exec). Callers must only invoke this from
// wave-uniform control flow.
// ---------------------------------------------------------------------------
static __device__ __forceinline__ float dot128_rl(const float* __restrict__ w,
                                                  float hv0, float hv1) {
    const int h0 = __float_as_int(hv0);
    const int h1 = __float_as_int(hv1);
    float a0 = 0.f, a1 = 0.f, a2 = 0.f, a3 = 0.f;
#pragma unroll
    for (int j = 0; j < 64; j += 4) {
        a0 = fmaf(w[j + 0], __int_as_float(__builtin_amdgcn_readlane(h0, j + 0)), a0);
        a1 = fmaf(w[j + 1], __int_as_float(__builtin_amdgcn_readlane(h0, j + 1)), a1);
        a2 = fmaf(w[j + 2], __int_as_float(__builtin_amdgcn_readlane(h0, j + 2)), a2);
        a3 = fmaf(w[j + 3], __int_as_float(__builtin_amdgcn_readlane(h0, j + 3)), a3);
    }
#pragma unroll
    for (int j = 0; j < 64; j += 4) {
        a0 = fmaf(w[64 + j + 0], __int_as_float(__builtin_amdgcn_readlane(h1, j + 0)), a0);
        a1 = fmaf(w[64 + j + 1], __int_as_float(__builtin_amdgcn_readlane(h1, j + 1)), a1);
        a2 = fmaf(w[64 + j + 2], __int_as_float(__builtin_amdgcn_readlane(h1, j + 2)), a2);
        a3 = fmaf(w[64 + j + 3], __int_as_float(__builtin_amdgcn_readlane(h1, j + 3)), a3);
    }
    return (a0 + a1) + (a2 + a3);
}

static __device__ __forceinline__ float sigm(float x) {
    return 1.0f / (1.0f + expf(-x));
}

// ---------------------------------------------------------------------------
// Fused GEMM:  C[m,n] = bias[n] + sum_k A1[m,k]*W[n, wofs1+k]  (K1 terms)
//                               + sum_k A2[m,k]*W[n, wofs2+k]  (K2 terms, A2 may be null)
// A row-major [M,lda], W row-major [N,ldw]. Tile 128x128, BK=8, 256 thr, 8x8 micro.
// ---------------------------------------------------------------------------
__global__ __launch_bounds__(256) void gemm_fused_kernel(
    const float* __restrict__ A1, int lda1, int K1, int wofs1,
    const float* __restrict__ A2, int lda2, int K2, int wofs2,
    const float* __restrict__ W, int ldw,
    const float* __restrict__ bias,
    float* __restrict__ C, int ldc)
{
    __shared__ float As[8][128];
    __shared__ float Bs[8][128];
    const int tid = threadIdx.x;
    const int m0 = blockIdx.x * 128;
    const int n0 = blockIdx.y * 128;
    const int lr = tid >> 1;           // 0..127 : tile row loaded by this thread
    const int lc = (tid & 1) << 2;     // 0 or 4 : k-offset loaded
    const int ty = tid >> 4;           // 0..15
    const int tx = tid & 15;           // 0..15

    float acc[8][8];
#pragma unroll
    for (int i = 0; i < 8; ++i)
#pragma unroll
        for (int j = 0; j < 8; ++j) acc[i][j] = 0.f;

#pragma unroll 1
    for (int phase = 0; phase < 2; ++phase) {
        const float* __restrict__ A = phase ? A2 : A1;
        if (A == nullptr) continue;
        const int lda  = phase ? lda2  : lda1;
        const int K    = phase ? K2    : K1;
        const int wofs = phase ? wofs2 : wofs1;
        for (int k0 = 0; k0 < K; k0 += 8) {
            const int k = k0 + lc;
            float4 av = make_float4(0.f, 0.f, 0.f, 0.f);
            float4 bv = make_float4(0.f, 0.f, 0.f, 0.f);
            if (k < K) {
                av = *(const float4*)(A + (size_t)(m0 + lr) * lda + k);
                bv = *(const float4*)(W + (size_t)(n0 + lr) * ldw + wofs + k);
            }
            __syncthreads();
            As[lc + 0][lr] = av.x; As[lc + 1][lr] = av.y;
            As[lc + 2][lr] = av.z; As[lc + 3][lr] = av.w;
            Bs[lc + 0][lr] = bv.x; Bs[lc + 1][lr] = bv.y;
            Bs[lc + 2][lr] = bv.z; Bs[lc + 3][lr] = bv.w;
            __syncthreads();
#pragma unroll
            for (int kk = 0; kk < 8; ++kk) {
                float a[8], bb[8];
#pragma unroll
                for (int i = 0; i < 4; ++i) {
                    a[i]     = As[kk][ty * 4 + i];
                    a[4 + i] = As[kk][64 + ty * 4 + i];
                }
#pragma unroll
                for (int j = 0; j < 4; ++j) {
                    bb[j]     = Bs[kk][tx * 4 + j];
                    bb[4 + j] = Bs[kk][64 + tx * 4 + j];
                }
#pragma unroll
                for (int i = 0; i < 8; ++i)
#pragma unroll
                    for (int j = 0; j < 8; ++j)
                        acc[i][j] = fmaf(a[i], bb[j], acc[i][j]);
            }
        }
    }
#pragma unroll
    for (int i = 0; i < 8; ++i) {
        const int rr = m0 + ((i < 4) ? (ty * 4 + i) : (64 + ty * 4 + (i - 4)));
#pragma unroll
        for (int j = 0; j < 8; ++j) {
            const int cc = n0 + ((j < 4) ? (tx * 4 + j) : (64 + tx * 4 + (j - 4)));
            C[(size_t)rr * ldc + cc] = acc[i][j] + bias[cc];
        }
    }
}

// ---------------------------------------------------------------------------
// Bidirectional encoder GRU scans. 256 WGs (0..127 fwd batch b, 128..255 bwd),
// 384 threads: thread r owns Whh row r in 128 VGPRs (launch_bounds(.,2) keeps
// the 256-VGPR cap so the array does NOT spill — this was the round-2 stall).
// Per step: prefetch xp row -> readlane matvec -> gates on threads 0..127.
// ---------------------------------------------------------------------------
__global__ __launch_bounds__(384, 2) void enc_scan_kernel(
    const float* __restrict__ xp,      // xp_f, with xp_b at +TLEN*BATCH*G3
    const float* __restrict__ Whh_f, const float* __restrict__ bhh_f,
    const float* __restrict__ Whh_b, const float* __restrict__ bhh_b,
    const float* __restrict__ enc_init,
    float* __restrict__ g)             // [T*B, 2*EDIM]
{
    const int wg  = blockIdx.x;
    const int dir = wg >> 7;
    const int b   = wg & 127;
    const int tid = threadIdx.x;
    const int lane = tid & 63;
    const float* __restrict__ Whh = dir ? Whh_b : Whh_f;
    const float* __restrict__ bhh = dir ? bhh_b : bhh_f;
    const float* __restrict__ xpd = xp + (size_t)dir * ((size_t)TLEN * BATCH * G3);

    __shared__ float h_lds[EDIM];
    __shared__ float hh_lds[G3];

    float w[128];
    {
        const float4* src = (const float4*)(Whh + (size_t)tid * 128);
#pragma unroll
        for (int i = 0; i < 32; ++i) {
            float4 v = src[i];
            w[4 * i] = v.x; w[4 * i + 1] = v.y; w[4 * i + 2] = v.z; w[4 * i + 3] = v.w;
        }
    }
    const float brow = bhh[tid];
    if (tid < EDIM) h_lds[tid] = enc_init[dir * EDIM + tid];
    __syncthreads();

    for (int s = 0; s < TLEN; ++s) {
        const int t = dir ? (TLEN - 1 - s) : s;
        const size_t row = (size_t)t * BATCH + b;
        // prefetch xp row BEFORE the long dot (consumed after barrier A)
        float xr = 0.f, xz = 0.f, xn = 0.f;
        if (tid < EDIM) {
            const float* xrow = xpd + row * G3;
            xr = xrow[tid]; xz = xrow[EDIM + tid]; xn = xrow[2 * EDIM + tid];
        }
        // unconditional loads + unconditional dot: readlane sees all lanes live
        const float hv0 = h_lds[lane];
        const float hv1 = h_lds[64 + lane];
        const float hh = dot128_rl(w, hv0, hv1) + brow;
        hh_lds[tid] = hh;
        __syncthreads();  // A
        if (tid < EDIM) {   // waves 0,1 fully active (wave-uniform branch)
            const float hr = hh_lds[tid], hz = hh_lds[EDIM + tid], hn = hh_lds[2 * EDIM + tid];
            const float r = sigm(xr + hr);
            const float z = sigm(xz + hz);
            const float n = tanhf(xn + r * hn);
            const float hold = h_lds[tid];
            const float hnew = (1.f - z) * n + z * hold;
            h_lds[tid] = hnew;
            g[row * (2 * EDIM) + dir * EDIM + tid] = fminf(fmaxf(hnew, -CLIPV), CLIPV);
        }
        __syncthreads();  // B
    }
}

// ---------------------------------------------------------------------------
// Controller GRU + latent sample + spike + AR1 calcium. 128 WGs (one per batch),
// 512 threads:
//   tid 0..383  : ctrl_Whh row (128 VGPRs) ; tid 0..319 also W_spk row (clamped)
//   tid 384..511: W_mu row (tid-384 < 64) or W_lv row  (128 VGPRs)
// launch_bounds(512,2): VGPR cap 256 so weight arrays stay in registers.
// 4 barriers/step (E removed: phase-C reads at iter t precede barrier A of
// t+1; all conflicting writes at t+1 occur after A/B/C of t+1).
// ALL branches containing readlane are wave-uniform.
// ---------------------------------------------------------------------------
__global__ __launch_bounds__(512, 2) void ctrl_scan_kernel(
    const float* __restrict__ cp,       // [T*B, 384]
    const float* __restrict__ factors,  // [T*B, 4]
    const float* __restrict__ eps,      // [T*B, 64]
    const float* __restrict__ Whh, const float* __restrict__ bhh,
    const float* __restrict__ ctrl_init,
    const float* __restrict__ W_mu, const float* __restrict__ b_mu,
    const float* __restrict__ W_lv, const float* __restrict__ b_lv,
    const float* __restrict__ W_spk, const float* __restrict__ b_spk,
    const float* __restrict__ gain_p, const float* __restrict__ bias_p_p,
    const float* __restrict__ logtau_p,
    float* __restrict__ out)            // [T*B, 300]
{
    const int b   = blockIdx.x;
    const int tid = threadIdx.x;
    const int lane = tid & 63;

    __shared__ float h_lds[CDIM];
    __shared__ float hh_lds[G3];
    __shared__ float lv_lds[UDIM];
    __shared__ float gen_lds[UDIM + FDIM];

    float wbig[128];
    float wspk[68];
    float bias_row = 0.f, bspk_r = 0.f;

    if (tid < G3) {
        const float4* src = (const float4*)(Whh + (size_t)tid * 128);
#pragma unroll
        for (int i = 0; i < 32; ++i) {
            float4 v = src[i];
            wbig[4 * i] = v.x; wbig[4 * i + 1] = v.y; wbig[4 * i + 2] = v.z; wbig[4 * i + 3] = v.w;
        }
        bias_row = bhh[tid];
    } else {
        const int mrow = tid - G3;
        const float* Wsrc = (mrow < UDIM) ? (W_mu + (size_t)mrow * 128)
                                          : (W_lv + (size_t)(mrow - UDIM) * 128);
        const float4* src = (const float4*)Wsrc;
#pragma unroll
        for (int i = 0; i < 32; ++i) {
            float4 v = src[i];
            wbig[4 * i] = v.x; wbig[4 * i + 1] = v.y; wbig[4 * i + 2] = v.z; wbig[4 * i + 3] = v.w;
        }
        bias_row = (mrow < UDIM) ? b_mu[mrow] : b_lv[mrow - UDIM];
    }
    if (tid < 320) {                    // wave-uniform: waves 0..4
        const int srow = (tid < NDIM) ? tid : (NDIM - 1);   // clamp pad threads
        const float4* src = (const float4*)(W_spk + (size_t)srow * 68);
#pragma unroll
        for (int i = 0; i < 17; ++i) {
            float4 v = src[i];
            wspk[4 * i] = v.x; wspk[4 * i + 1] = v.y; wspk[4 * i + 2] = v.z; wspk[4 * i + 3] = v.w;
        }
        bspk_r = b_spk[srow];
    }
    const float gain  = gain_p[0];
    const float biasp = bias_p_p[0];
    const float decay = 1.0f - expf(-logtau_p[0]);
    if (tid < CDIM) h_lds[tid] = ctrl_init[tid];
    float cal = 0.0f;
    __syncthreads();

    float hv0 = h_lds[lane];
    float hv1 = h_lds[64 + lane];

    for (int t = 0; t < TLEN; ++t) {
        const size_t row = (size_t)t * BATCH + b;
        // ---- prefetch this step's global rows BEFORE the long dot ----
        float cxr = 0.f, cxz = 0.f, cxn = 0.f;   // cp row (gates, after barrier A)
        float epv = 0.f;                          // eps    (gen, after barrier C)
        float fv  = 0.f;                          // factors (LDS write, after A)
        if (tid < CDIM) {
            const float* cpr = cp + row * G3;
            cxr = cpr[tid]; cxz = cpr[CDIM + tid]; cxn = cpr[2 * CDIM + tid];
        }
        if (tid >= G3 && tid < G3 + UDIM) epv = eps[row * UDIM + (tid - G3)];
        if (tid >= 448 && tid < 448 + FDIM) fv = factors[row * FDIM + (tid - 448)];

        // ---- phase A: recurrent matvec hh = Whh @ h + bhh (waves 0..5) ----
        if (tid < G3) hh_lds[tid] = dot128_rl(wbig, hv0, hv1) + bias_row;
        __syncthreads();  // A
        // ---- gates (threads 0..127, waves 0,1), clip state ----
        if (tid < CDIM) {
            const float hr = hh_lds[tid], hz = hh_lds[CDIM + tid], hn = hh_lds[2 * CDIM + tid];
            const float r = sigm(cxr + hr);
            const float z = sigm(cxz + hz);
            const float n = tanhf(cxn + r * hn);
            const float hold = h_lds[tid];
            float hnew = (1.f - z) * n + z * hold;
            hnew = fminf(fmaxf(hnew, -CLIPV), CLIPV);
            h_lds[tid] = hnew;
        }
        if (tid >= 448 && tid < 448 + FDIM) {
            gen_lds[UDIM + (tid - 448)] = fv;
        }
        __syncthreads();  // B
        hv0 = h_lds[lane];         // reload new h (used by mu/lv now, Whh next step)
        hv1 = h_lds[64 + lane];
        // ---- phase B: mu / lv (threads 384..511, waves 6,7) ----
        float muv = 0.f;
        if (tid >= G3) {
            const float v = dot128_rl(wbig, hv0, hv1) + bias_row;
            const int mrow = tid - G3;
            if (mrow < UDIM) muv = v; else lv_lds[mrow - UDIM] = v;
        }
        __syncthreads();  // C
        if (tid >= G3 && tid < G3 + UDIM) {
            const int j = tid - G3;
            gen_lds[j] = muv + expf(0.5f * lv_lds[j]) * epv;
        }
        __syncthreads();  // D
        // ---- phase C: spike + calcium (waves 0..4, WAVE-UNIFORM branch) ----
        if (tid < 320) {
            const float gval = gen_lds[lane];   // all 64 lanes of waves 0..4 live
            const int gvi = __float_as_int(gval);
            float a0 = 0.f, a1 = 0.f, a2 = 0.f, a3 = 0.f;
#pragma unroll
            for (int j = 0; j < 64; j += 4) {
                a0 = fmaf(wspk[j + 0], __int_as_float(__builtin_amdgcn_readlane(gvi, j + 0)), a0);
                a1 = fmaf(wspk[j + 1], __int_as_float(__builtin_amdgcn_readlane(gvi, j + 1)), a1);
                a2 = fmaf(wspk[j + 2], __int_as_float(__builtin_amdgcn_readlane(gvi, j + 2)), a2);
                a3 = fmaf(wspk[j + 3], __int_as_float(__builtin_amdgcn_readlane(gvi, j + 3)), a3);
            }
            float acc = (a0 + a1) + (a2 + a3);
#pragma unroll
            for (int q = 0; q < FDIM; ++q) acc = fmaf(wspk[64 + q], gen_lds[UDIM + q], acc);
            acc += bspk_r;
            const float sp = fmaxf(expf(acc) - 1.0f, 0.0f);
            cal = cal * decay + gain * sp + biasp;
            if (tid < NDIM) out[row * NDIM + tid] = cal;  // only the store diverges
        }
        // no barrier E: phase-C reads precede barrier A of next iter; all
        // conflicting writes next iter occur after that barrier (see header).
    }
}

// ---------------------------------------------------------------------------
extern "C" void kernel_launch(void* const* d_in, const int* in_sizes, int n_in,
                              void* d_out, int out_size, void* d_ws, size_t ws_size,
                              hipStream_t stream) {
    const float* x         = (const float*)d_in[0];
    const float* factors   = (const float*)d_in[1];
    const float* eps       = (const float*)d_in[2];
    const float* enc_Wih_f = (const float*)d_in[3];
    const float* enc_Whh_f = (const float*)d_in[4];
    const float* enc_bih_f = (const float*)d_in[5];
    const float* enc_bhh_f = (const float*)d_in[6];
    const float* enc_Wih_b = (const float*)d_in[7];
    const float* enc_Whh_b = (const float*)d_in[8];
    const float* enc_bih_b = (const float*)d_in[9];
    const float* enc_bhh_b = (const float*)d_in[10];
    const float* enc_init  = (const float*)d_in[11];
    const float* ctrl_Wih  = (const float*)d_in[12];
    const float* ctrl_Whh  = (const float*)d_in[13];
    const float* ctrl_bih  = (const float*)d_in[14];
    const float* ctrl_bhh  = (const float*)d_in[15];
    const float* ctrl_init = (const float*)d_in[16];
    const float* W_mu      = (const float*)d_in[17];
    const float* b_mu      = (const float*)d_in[18];
    const float* W_lv      = (const float*)d_in[19];
    const float* b_lv      = (const float*)d_in[20];
    const float* W_spk     = (const float*)d_in[21];
    const float* b_spk     = (const float*)d_in[22];
    const float* gain      = (const float*)d_in[23];
    const float* bias_p    = (const float*)d_in[24];
    const float* logtau    = (const float*)d_in[25];
    float* out = (float*)d_out;
    float* ws  = (float*)d_ws;

    const size_t PROJ = (size_t)TLEN * BATCH * G3;   // 24,576,000 floats
    float* xpf = ws;
    float* xpb = ws + PROJ;
    float* g   = ws + 2 * PROJ;                      // [T*B, 256]
    float* cp  = ws;                                 // reuse xpf region after encoder

    dim3 ggrid(500, 3);  // M/128 = 64000/128, N/128 = 384/128

    // xp_f = x @ enc_Wih_f.T + bih_f ; xp_b = x @ enc_Wih_b.T + bih_b
    gemm_fused_kernel<<<ggrid, 256, 0, stream>>>(x, NDIM, NDIM, 0,
                                                 nullptr, 0, 0, 0,
                                                 enc_Wih_f, NDIM, enc_bih_f, xpf, G3);
    gemm_fused_kernel<<<ggrid, 256, 0, stream>>>(x, NDIM, NDIM, 0,
                                                 nullptr, 0, 0, 0,
                                                 enc_Wih_b, NDIM, enc_bih_b, xpb, G3);
    // bidirectional encoder scans -> g (clipped)
    enc_scan_kernel<<<256, 384, 0, stream>>>(xpf, enc_Whh_f, enc_bhh_f,
                                             enc_Whh_b, enc_bhh_b, enc_init, g);
    // cp = g @ ctrl_Wih[:, :256].T + x @ ctrl_Wih[:, 256:].T + ctrl_bih
    gemm_fused_kernel<<<ggrid, 256, 0, stream>>>(g, 2 * EDIM, 2 * EDIM, 0,
                                                 x, NDIM, NDIM, 2 * EDIM,
                                                 ctrl_Wih, 2 * EDIM + NDIM, ctrl_bih, cp, G3);
    // controller scan + latent + spike + calcium -> out
    ctrl_scan_kernel<<<128, 512, 0, stream>>>(cp, factors, eps,
                                              ctrl_Whh, ctrl_bhh, ctrl_init,
                                              W_mu, b_mu, W_lv, b_lv,
                                              W_spk, b_spk,
                                              gain, bias_p, logtau, out);
}

// Round 5
// 2577.236 us; speedup vs baseline: 1.1858x; 1.0079x over previous
//
#include <hip/hip_runtime.h>
#include <cstdint>
#include <cstddef>

#define TLEN 500
#define BATCH 128
#define NDIM 300
#define EDIM 128
#define CDIM 128
#define UDIM 64
#define FDIM 4
#define G3 384           // 3*E == 3*C
#define CLIPV 5.0f

// ---------------------------------------------------------------------------
// Repetition macros: weight rows are held in NAMED float4 variables (w0..w31,
// s0..s16), never in a local array. Round-3 rocprof showed VGPR_Count=112 with
// arrays: AMDGPU leaves >512B allocas in scratch, so every dot-FMA was fed by
// a ~200cy scratch load (VALUBusy 21%). Named scalars force VGPR residency.
// ---------------------------------------------------------------------------
#define REP32(M) M(0) M(1) M(2) M(3) M(4) M(5) M(6) M(7) \
                 M(8) M(9) M(10) M(11) M(12) M(13) M(14) M(15) \
                 M(16) M(17) M(18) M(19) M(20) M(21) M(22) M(23) \
                 M(24) M(25) M(26) M(27) M(28) M(29) M(30) M(31)
#define REP16(M) M(0) M(1) M(2) M(3) M(4) M(5) M(6) M(7) \
                 M(8) M(9) M(10) M(11) M(12) M(13) M(14) M(15)
#define REP17(M) REP16(M) M(16)

#define DECLW(i) float4 w##i = wsrc[i];
#define DECLS(i) float4 s##i = ssrc[i];

// broadcast h element j (0..127) from lane registers h0/h1 (readlane needs all
// 64 lanes of the wave live -> only call from wave-uniform control flow)
#define RLH(j) __int_as_float(__builtin_amdgcn_readlane(((j) < 64) ? h0 : h1, (j) & 63))
#define DOTW(i) a0 = fmaf(w##i.x, RLH(4*(i)+0), a0); \
                a1 = fmaf(w##i.y, RLH(4*(i)+1), a1); \
                a2 = fmaf(w##i.z, RLH(4*(i)+2), a2); \
                a3 = fmaf(w##i.w, RLH(4*(i)+3), a3);

// broadcast gen element j (0..63) from lane register gvi
#define RLG(j) __int_as_float(__builtin_amdgcn_readlane(gvi, (j)))
#define DOTS(i) c0 = fmaf(s##i.x, RLG(4*(i)+0), c0); \
                c1 = fmaf(s##i.y, RLG(4*(i)+1), c1); \
                c2 = fmaf(s##i.z, RLG(4*(i)+2), c2); \
                c3 = fmaf(s##i.w, RLG(4*(i)+3), c3);

static __device__ __forceinline__ float sigm(float x) {
    return 1.0f / (1.0f + expf(-x));
}

// ---------------------------------------------------------------------------
// Fused GEMM:  C[m,n] = bias[n] + sum_k A1[m,k]*W[n, wofs1+k]  (K1 terms)
//                               + sum_k A2[m,k]*W[n, wofs2+k]  (K2 terms, A2 may be null)
// A row-major [M,lda], W row-major [N,ldw]. Tile 128x128, BK=8, 256 thr, 8x8 micro.
// ---------------------------------------------------------------------------
__global__ __launch_bounds__(256) void gemm_fused_kernel(
    const float* __restrict__ A1, int lda1, int K1, int wofs1,
    const float* __restrict__ A2, int lda2, int K2, int wofs2,
    const float* __restrict__ W, int ldw,
    const float* __restrict__ bias,
    float* __restrict__ C, int ldc)
{
    __shared__ float As[8][128];
    __shared__ float Bs[8][128];
    const int tid = threadIdx.x;
    const int m0 = blockIdx.x * 128;
    const int n0 = blockIdx.y * 128;
    const int lr = tid >> 1;           // 0..127 : tile row loaded by this thread
    const int lc = (tid & 1) << 2;     // 0 or 4 : k-offset loaded
    const int ty = tid >> 4;           // 0..15
    const int tx = tid & 15;           // 0..15

    float acc[8][8];
#pragma unroll
    for (int i = 0; i < 8; ++i)
#pragma unroll
        for (int j = 0; j < 8; ++j) acc[i][j] = 0.f;

#pragma unroll 1
    for (int phase = 0; phase < 2; ++phase) {
        const float* __restrict__ A = phase ? A2 : A1;
        if (A == nullptr) continue;
        const int lda  = phase ? lda2  : lda1;
        const int K    = phase ? K2    : K1;
        const int wofs = phase ? wofs2 : wofs1;
        for (int k0 = 0; k0 < K; k0 += 8) {
            const int k = k0 + lc;
            float4 av = make_float4(0.f, 0.f, 0.f, 0.f);
            float4 bv = make_float4(0.f, 0.f, 0.f, 0.f);
            if (k < K) {
                av = *(const float4*)(A + (size_t)(m0 + lr) * lda + k);
                bv = *(const float4*)(W + (size_t)(n0 + lr) * ldw + wofs + k);
            }
            __syncthreads();
            As[lc + 0][lr] = av.x; As[lc + 1][lr] = av.y;
            As[lc + 2][lr] = av.z; As[lc + 3][lr] = av.w;
            Bs[lc + 0][lr] = bv.x; Bs[lc + 1][lr] = bv.y;
            Bs[lc + 2][lr] = bv.z; Bs[lc + 3][lr] = bv.w;
            __syncthreads();
#pragma unroll
            for (int kk = 0; kk < 8; ++kk) {
                float a[8], bb[8];
#pragma unroll
                for (int i = 0; i < 4; ++i) {
                    a[i]     = As[kk][ty * 4 + i];
                    a[4 + i] = As[kk][64 + ty * 4 + i];
                }
#pragma unroll
                for (int j = 0; j < 4; ++j) {
                    bb[j]     = Bs[kk][tx * 4 + j];
                    bb[4 + j] = Bs[kk][64 + tx * 4 + j];
                }
#pragma unroll
                for (int i = 0; i < 8; ++i)
#pragma unroll
                    for (int j = 0; j < 8; ++j)
                        acc[i][j] = fmaf(a[i], bb[j], acc[i][j]);
            }
        }
    }
#pragma unroll
    for (int i = 0; i < 8; ++i) {
        const int rr = m0 + ((i < 4) ? (ty * 4 + i) : (64 + ty * 4 + (i - 4)));
#pragma unroll
        for (int j = 0; j < 8; ++j) {
            const int cc = n0 + ((j < 4) ? (tx * 4 + j) : (64 + tx * 4 + (j - 4)));
            C[(size_t)rr * ldc + cc] = acc[i][j] + bias[cc];
        }
    }
}

// ---------------------------------------------------------------------------
// Bidirectional encoder GRU scans. 256 WGs (0..127 fwd batch b, 128..255 bwd),
// 384 threads: thread r owns Whh row r in 32 NAMED float4 registers.
// Per step: prefetch xp row -> readlane matvec -> gates on threads 0..127.
// NOTE (R4 bug fixed): for the gate update, h_lds[tid] is h0 only on wave 0
// (tid<64); on wave 1 (tid 64..127) it is h1. Use a per-lane select.
// ---------------------------------------------------------------------------
__global__ __launch_bounds__(384, 2) void enc_scan_kernel(
    const float* __restrict__ xp,      // xp_f, with xp_b at +TLEN*BATCH*G3
    const float* __restrict__ Whh_f, const float* __restrict__ bhh_f,
    const float* __restrict__ Whh_b, const float* __restrict__ bhh_b,
    const float* __restrict__ enc_init,
    float* __restrict__ g)             // [T*B, 2*EDIM]
{
    const int wg  = blockIdx.x;
    const int dir = wg >> 7;
    const int b   = wg & 127;
    const int tid = threadIdx.x;
    const int lane = tid & 63;
    const float* __restrict__ Whh = dir ? Whh_b : Whh_f;
    const float* __restrict__ bhh = dir ? bhh_b : bhh_f;
    const float* __restrict__ xpd = xp + (size_t)dir * ((size_t)TLEN * BATCH * G3);

    __shared__ float h_lds[EDIM];
    __shared__ float hh_lds[G3];

    const float4* wsrc = (const float4*)(Whh + (size_t)tid * 128);
    REP32(DECLW)                       // float4 w0..w31 = this thread's Whh row

    const float brow = bhh[tid];
    if (tid < EDIM) h_lds[tid] = enc_init[dir * EDIM + tid];
    __syncthreads();

    for (int s = 0; s < TLEN; ++s) {
        const int t = dir ? (TLEN - 1 - s) : s;
        const size_t row = (size_t)t * BATCH + b;
        // prefetch xp row BEFORE the long dot (consumed after barrier A)
        float xr = 0.f, xz = 0.f, xn = 0.f;
        if (tid < EDIM) {
            const float* xrow = xpd + row * G3;
            xr = xrow[tid]; xz = xrow[EDIM + tid]; xn = xrow[2 * EDIM + tid];
        }
        // unconditional loads + unconditional dot: readlane sees all lanes live
        const int h0 = __float_as_int(h_lds[lane]);
        const int h1 = __float_as_int(h_lds[64 + lane]);
        float a0 = 0.f, a1 = 0.f, a2 = 0.f, a3 = 0.f;
        REP32(DOTW)
        hh_lds[tid] = ((a0 + a1) + (a2 + a3)) + brow;
        __syncthreads();  // A
        if (tid < EDIM) {   // waves 0,1 fully active (wave-uniform branch)
            const float hr = hh_lds[tid], hz = hh_lds[EDIM + tid], hn = hh_lds[2 * EDIM + tid];
            const float r = sigm(xr + hr);
            const float z = sigm(xz + hz);
            const float n = tanhf(xn + r * hn);
            // h_lds[tid]: wave 0 -> h0 (lane==tid), wave 1 -> h1 (64+lane==tid)
            const float hold = (tid < 64) ? __int_as_float(h0) : __int_as_float(h1);
            const float hnew = (1.f - z) * n + z * hold;
            h_lds[tid] = hnew;
            g[row * (2 * EDIM) + dir * EDIM + tid] = fminf(fmaxf(hnew, -CLIPV), CLIPV);
        }
        __syncthreads();  // B
    }
}

// ---------------------------------------------------------------------------
// Controller GRU + latent sample + spike + AR1 calcium. 128 WGs (one per batch),
// 512 threads:
//   tid 0..383  : ctrl_Whh row in w0..w31 ; tid 384..511: W_mu/W_lv row there
//   all threads : W_spk row (clamped) in s0..s16 (only waves 0..4 use it)
// All weights in NAMED float4 VGPRs (no alloca -> no scratch).
// 4 barriers/step; all readlane branches wave-uniform (verified R1-R3).
// NOTE (R4 bug fixed): gate 'hold' uses per-lane select h0/h1, see enc_scan.
// ---------------------------------------------------------------------------
__global__ __launch_bounds__(512, 2) void ctrl_scan_kernel(
    const float* __restrict__ cp,       // [T*B, 384]
    const float* __restrict__ factors,  // [T*B, 4]
    const float* __restrict__ eps,      // [T*B, 64]
    const float* __restrict__ Whh, const float* __restrict__ bhh,
    const float* __restrict__ ctrl_init,
    const float* __restrict__ W_mu, const float* __restrict__ b_mu,
    const float* __restrict__ W_lv, const float* __restrict__ b_lv,
    const float* __restrict__ W_spk, const float* __restrict__ b_spk,
    const float* __restrict__ gain_p, const float* __restrict__ bias_p_p,
    const float* __restrict__ logtau_p,
    float* __restrict__ out)            // [T*B, 300]
{
    const int b   = blockIdx.x;
    const int tid = threadIdx.x;
    const int lane = tid & 63;

    __shared__ float h_lds[CDIM];
    __shared__ float hh_lds[G3];
    __shared__ float lv_lds[UDIM];
    __shared__ float gen_lds[UDIM + FDIM];

    // ---- select this thread's 128-wide weight row, then load into w0..w31 ----
    const float* wptr;
    float bias_row;
    if (tid < G3) {
        wptr = Whh + (size_t)tid * 128;
        bias_row = bhh[tid];
    } else {
        const int mrow = tid - G3;
        if (mrow < UDIM) { wptr = W_mu + (size_t)mrow * 128; bias_row = b_mu[mrow]; }
        else             { wptr = W_lv + (size_t)(mrow - UDIM) * 128; bias_row = b_lv[mrow - UDIM]; }
    }
    const float4* wsrc = (const float4*)wptr;
    REP32(DECLW)                       // float4 w0..w31

    // ---- W_spk row (clamped for pad threads; loaded by ALL threads) ----
    const int srow = (tid < NDIM) ? tid : (NDIM - 1);
    const float4* ssrc = (const float4*)(W_spk + (size_t)srow * 68);
    REP17(DECLS)                       // float4 s0..s16 (s16 = factor weights)
    const float bspk_r = b_spk[srow];

    const float gain  = gain_p[0];
    const float biasp = bias_p_p[0];
    const float decay = 1.0f - expf(-logtau_p[0]);
    if (tid < CDIM) h_lds[tid] = ctrl_init[tid];
    float cal = 0.0f;
    __syncthreads();

    int h0 = __float_as_int(h_lds[lane]);
    int h1 = __float_as_int(h_lds[64 + lane]);

    for (int t = 0; t < TLEN; ++t) {
        const size_t row = (size_t)t * BATCH + b;
        // ---- prefetch this step's global rows BEFORE the long dot ----
        float cxr = 0.f, cxz = 0.f, cxn = 0.f;   // cp row (gates, after barrier A)
        float epv = 0.f;                          // eps    (gen, after barrier C)
        float fv  = 0.f;                          // factors (LDS write, after A)
        if (tid < CDIM) {
            const float* cpr = cp + row * G3;
            cxr = cpr[tid]; cxz = cpr[CDIM + tid]; cxn = cpr[2 * CDIM + tid];
        }
        if (tid >= G3 && tid < G3 + UDIM) epv = eps[row * UDIM + (tid - G3)];
        if (tid >= 448 && tid < 448 + FDIM) fv = factors[row * FDIM + (tid - 448)];

        // ---- phase A: hh = Whh @ h + bhh (waves 0..5, wave-uniform) ----
        if (tid < G3) {
            float a0 = 0.f, a1 = 0.f, a2 = 0.f, a3 = 0.f;
            REP32(DOTW)
            hh_lds[tid] = ((a0 + a1) + (a2 + a3)) + bias_row;
        }
        __syncthreads();  // A
        // ---- gates (threads 0..127, waves 0,1), clip state ----
        if (tid < CDIM) {
            const float hr = hh_lds[tid], hz = hh_lds[CDIM + tid], hn = hh_lds[2 * CDIM + tid];
            const float r = sigm(cxr + hr);
            const float z = sigm(cxz + hz);
            const float n = tanhf(cxn + r * hn);
            // h_lds[tid]: wave 0 -> h0, wave 1 -> h1 (R4 bug was using h0 for both)
            const float hold = (tid < 64) ? __int_as_float(h0) : __int_as_float(h1);
            float hnew = (1.f - z) * n + z * hold;
            hnew = fminf(fmaxf(hnew, -CLIPV), CLIPV);
            h_lds[tid] = hnew;
        }
        if (tid >= 448 && tid < 448 + FDIM) {
            gen_lds[UDIM + (tid - 448)] = fv;
        }
        __syncthreads();  // B
        h0 = __float_as_int(h_lds[lane]);        // reload new h (all lanes live)
        h1 = __float_as_int(h_lds[64 + lane]);
        // ---- phase B: mu / lv (threads 384..511, waves 6,7, wave-uniform) ----
        float muv = 0.f;
        if (tid >= G3) {
            float a0 = 0.f, a1 = 0.f, a2 = 0.f, a3 = 0.f;
            REP32(DOTW)
            const float v = ((a0 + a1) + (a2 + a3)) + bias_row;
            const int mrow = tid - G3;
            if (mrow < UDIM) muv = v; else lv_lds[mrow - UDIM] = v;
        }
        __syncthreads();  // C
        if (tid >= G3 && tid < G3 + UDIM) {
            const int j = tid - G3;
            gen_lds[j] = muv + expf(0.5f * lv_lds[j]) * epv;
        }
        __syncthreads();  // D
        // ---- phase C: spike + calcium (waves 0..4, WAVE-UNIFORM branch) ----
        if (tid < 320) {
            const int gvi = __float_as_int(gen_lds[lane]);  // all 64 lanes live
            float c0 = 0.f, c1 = 0.f, c2 = 0.f, c3 = 0.f;
            REP16(DOTS)
            float acc = (c0 + c1) + (c2 + c3);
            acc = fmaf(s16.x, gen_lds[UDIM + 0], acc);
            acc = fmaf(s16.y, gen_lds[UDIM + 1], acc);
            acc = fmaf(s16.z, gen_lds[UDIM + 2], acc);
            acc = fmaf(s16.w, gen_lds[UDIM + 3], acc);
            acc += bspk_r;
            const float sp = fmaxf(expf(acc) - 1.0f, 0.0f);
            cal = cal * decay + gain * sp + biasp;
            if (tid < NDIM) out[row * NDIM + tid] = cal;  // only the store diverges
        }
        // no barrier E: phase-C reads precede barrier A of next iter; all
        // conflicting writes next iter occur after that barrier (see R2 proof).
    }
}

// ---------------------------------------------------------------------------
extern "C" void kernel_launch(void* const* d_in, const int* in_sizes, int n_in,
                              void* d_out, int out_size, void* d_ws, size_t ws_size,
                              hipStream_t stream) {
    const float* x         = (const float*)d_in[0];
    const float* factors   = (const float*)d_in[1];
    const float* eps       = (const float*)d_in[2];
    const float* enc_Wih_f = (const float*)d_in[3];
    const float* enc_Whh_f = (const float*)d_in[4];
    const float* enc_bih_f = (const float*)d_in[5];
    const float* enc_bhh_f = (const float*)d_in[6];
    const float* enc_Wih_b = (const float*)d_in[7];
    const float* enc_Whh_b = (const float*)d_in[8];
    const float* enc_bih_b = (const float*)d_in[9];
    const float* enc_bhh_b = (const float*)d_in[10];
    const float* enc_init  = (const float*)d_in[11];
    const float* ctrl_Wih  = (const float*)d_in[12];
    const float* ctrl_Whh  = (const float*)d_in[13];
    const float* ctrl_bih  = (const float*)d_in[14];
    const float* ctrl_bhh  = (const float*)d_in[15];
    const float* ctrl_init = (const float*)d_in[16];
    const float* W_mu      = (const float*)d_in[17];
    const float* b_mu      = (const float*)d_in[18];
    const float* W_lv      = (const float*)d_in[19];
    const float* b_lv      = (const float*)d_in[20];
    const float* W_spk     = (const float*)d_in[21];
    const float* b_spk     = (const float*)d_in[22];
    const float* gain      = (const float*)d_in[23];
    const float* bias_p    = (const float*)d_in[24];
    const float* logtau    = (const float*)d_in[25];
    float* out = (float*)d_out;
    float* ws  = (float*)d_ws;

    const size_t PROJ = (size_t)TLEN * BATCH * G3;   // 24,576,000 floats
    float* xpf = ws;
    float* xpb = ws + PROJ;
    float* g   = ws + 2 * PROJ;                      // [T*B, 256]
    float* cp  = ws;                                 // reuse xpf region after encoder

    dim3 ggrid(500, 3);  // M/128 = 64000/128, N/128 = 384/128

    // xp_f = x @ enc_Wih_f.T + bih_f ; xp_b = x @ enc_Wih_b.T + bih_b
    gemm_fused_kernel<<<ggrid, 256, 0, stream>>>(x, NDIM, NDIM, 0,
                                                 nullptr, 0, 0, 0,
                                                 enc_Wih_f, NDIM, enc_bih_f, xpf, G3);
    gemm_fused_kernel<<<ggrid, 256, 0, stream>>>(x, NDIM, NDIM, 0,
                                                 nullptr, 0, 0, 0,
                                                 enc_Wih_b, NDIM, enc_bih_b, xpb, G3);
    // bidirectional encoder scans -> g (clipped)
    enc_scan_kernel<<<256, 384, 0, stream>>>(xpf, enc_Whh_f, enc_bhh_f,
                                             enc_Whh_b, enc_bhh_b, enc_init, g);
    // cp = g @ ctrl_Wih[:, :256].T + x @ ctrl_Wih[:, 256:].T + ctrl_bih
    gemm_fused_kernel<<<ggrid, 256, 0, stream>>>(g, 2 * EDIM, 2 * EDIM, 0,
                                                 x, NDIM, NDIM, 2 * EDIM,
                                                 ctrl_Wih, 2 * EDIM + NDIM, ctrl_bih, cp, G3);
    // controller scan + latent + spike + calcium -> out
    ctrl_scan_kernel<<<128, 512, 0, stream>>>(cp, factors, eps,
                                              ctrl_Whh, ctrl_bhh, ctrl_init,
                                              W_mu, b_mu, W_lv, b_lv,
                                              W_spk, b_spk,
                                              gain, bias_p, logtau, out);
}

// Round 6
// 2573.007 us; speedup vs baseline: 1.1877x; 1.0016x over previous
//
#include <hip/hip_runtime.h>
#include <cstdint>
#include <cstddef>

#define TLEN 500
#define BATCH 128
#define NDIM 300
#define EDIM 128
#define CDIM 128
#define UDIM 64
#define FDIM 4
#define G3 384           // 3*E == 3*C
#define CLIPV 5.0f

// ---------------------------------------------------------------------------
// Weight rows live in named float4 SSA values w0..w31 / s0..s16. R5 showed the
// allocator REMATERIALIZES the loads into the loop when it may (const+restrict
// pointers) to chase occupancy (VGPR_Count stayed 116). Countermeasures here:
//  (a) amdgpu_waves_per_eu(2,2): target occupancy exactly 2 waves/EU ->
//      256-reg budget, no remat-for-occupancy incentive;
//  (b) weight and output pointers are NOT restrict-qualified, so out-stores
//      may alias the weights -> re-loading them mid-loop is illegal -> the
//      values must stay live in VGPRs.
// Stream inputs (xp/cp/eps/factors) stay __restrict__ so their in-loop loads
// don't inherit store-ordering waits.
// ---------------------------------------------------------------------------
#define REP32(M) M(0) M(1) M(2) M(3) M(4) M(5) M(6) M(7) \
                 M(8) M(9) M(10) M(11) M(12) M(13) M(14) M(15) \
                 M(16) M(17) M(18) M(19) M(20) M(21) M(22) M(23) \
                 M(24) M(25) M(26) M(27) M(28) M(29) M(30) M(31)
#define REP16(M) M(0) M(1) M(2) M(3) M(4) M(5) M(6) M(7) \
                 M(8) M(9) M(10) M(11) M(12) M(13) M(14) M(15)
#define REP17(M) REP16(M) M(16)

#define DECLW(i) float4 w##i = wsrc[i];
#define DECLS(i) float4 s##i = ssrc[i];

// broadcast h element j (0..127) from lane registers h0/h1 (readlane needs all
// 64 lanes of the wave live -> only call from wave-uniform control flow)
#define RLH(j) __int_as_float(__builtin_amdgcn_readlane(((j) < 64) ? h0 : h1, (j) & 63))
#define DOTW(i) a0 = fmaf(w##i.x, RLH(4*(i)+0), a0); \
                a1 = fmaf(w##i.y, RLH(4*(i)+1), a1); \
                a2 = fmaf(w##i.z, RLH(4*(i)+2), a2); \
                a3 = fmaf(w##i.w, RLH(4*(i)+3), a3);

// broadcast gen element j (0..63) from lane register gvi
#define RLG(j) __int_as_float(__builtin_amdgcn_readlane(gvi, (j)))
#define DOTS(i) c0 = fmaf(s##i.x, RLG(4*(i)+0), c0); \
                c1 = fmaf(s##i.y, RLG(4*(i)+1), c1); \
                c2 = fmaf(s##i.z, RLG(4*(i)+2), c2); \
                c3 = fmaf(s##i.w, RLG(4*(i)+3), c3);

static __device__ __forceinline__ float sigm(float x) {
    return 1.0f / (1.0f + expf(-x));
}

// ---------------------------------------------------------------------------
// Fused GEMM:  C[m,n] = bias[n] + sum_k A1[m,k]*W[n, wofs1+k]  (K1 terms)
//                               + sum_k A2[m,k]*W[n, wofs2+k]  (K2 terms, A2 may be null)
// A row-major [M,lda], W row-major [N,ldw]. Tile 128x128, BK=8, 256 thr, 8x8 micro.
// ---------------------------------------------------------------------------
__global__ __launch_bounds__(256) void gemm_fused_kernel(
    const float* __restrict__ A1, int lda1, int K1, int wofs1,
    const float* __restrict__ A2, int lda2, int K2, int wofs2,
    const float* __restrict__ W, int ldw,
    const float* __restrict__ bias,
    float* __restrict__ C, int ldc)
{
    __shared__ float As[8][128];
    __shared__ float Bs[8][128];
    const int tid = threadIdx.x;
    const int m0 = blockIdx.x * 128;
    const int n0 = blockIdx.y * 128;
    const int lr = tid >> 1;           // 0..127 : tile row loaded by this thread
    const int lc = (tid & 1) << 2;     // 0 or 4 : k-offset loaded
    const int ty = tid >> 4;           // 0..15
    const int tx = tid & 15;           // 0..15

    float acc[8][8];
#pragma unroll
    for (int i = 0; i < 8; ++i)
#pragma unroll
        for (int j = 0; j < 8; ++j) acc[i][j] = 0.f;

#pragma unroll 1
    for (int phase = 0; phase < 2; ++phase) {
        const float* __restrict__ A = phase ? A2 : A1;
        if (A == nullptr) continue;
        const int lda  = phase ? lda2  : lda1;
        const int K    = phase ? K2    : K1;
        const int wofs = phase ? wofs2 : wofs1;
        for (int k0 = 0; k0 < K; k0 += 8) {
            const int k = k0 + lc;
            float4 av = make_float4(0.f, 0.f, 0.f, 0.f);
            float4 bv = make_float4(0.f, 0.f, 0.f, 0.f);
            if (k < K) {
                av = *(const float4*)(A + (size_t)(m0 + lr) * lda + k);
                bv = *(const float4*)(W + (size_t)(n0 + lr) * ldw + wofs + k);
            }
            __syncthreads();
            As[lc + 0][lr] = av.x; As[lc + 1][lr] = av.y;
            As[lc + 2][lr] = av.z; As[lc + 3][lr] = av.w;
            Bs[lc + 0][lr] = bv.x; Bs[lc + 1][lr] = bv.y;
            Bs[lc + 2][lr] = bv.z; Bs[lc + 3][lr] = bv.w;
            __syncthreads();
#pragma unroll
            for (int kk = 0; kk < 8; ++kk) {
                float a[8], bb[8];
#pragma unroll
                for (int i = 0; i < 4; ++i) {
                    a[i]     = As[kk][ty * 4 + i];
                    a[4 + i] = As[kk][64 + ty * 4 + i];
                }
#pragma unroll
                for (int j = 0; j < 4; ++j) {
                    bb[j]     = Bs[kk][tx * 4 + j];
                    bb[4 + j] = Bs[kk][64 + tx * 4 + j];
                }
#pragma unroll
                for (int i = 0; i < 8; ++i)
#pragma unroll
                    for (int j = 0; j < 8; ++j)
                        acc[i][j] = fmaf(a[i], bb[j], acc[i][j]);
            }
        }
    }
#pragma unroll
    for (int i = 0; i < 8; ++i) {
        const int rr = m0 + ((i < 4) ? (ty * 4 + i) : (64 + ty * 4 + (i - 4)));
#pragma unroll
        for (int j = 0; j < 8; ++j) {
            const int cc = n0 + ((j < 4) ? (tx * 4 + j) : (64 + tx * 4 + (j - 4)));
            C[(size_t)rr * ldc + cc] = acc[i][j] + bias[cc];
        }
    }
}

// ---------------------------------------------------------------------------
// Bidirectional encoder GRU scans. 256 WGs (0..127 fwd batch b, 128..255 bwd),
// 384 threads: thread r owns Whh row r in w0..w31 (VGPR-resident; see header).
// Whh/bhh/g are NOT restrict: g-stores may alias them -> no mid-loop remat.
// ---------------------------------------------------------------------------
__attribute__((amdgpu_waves_per_eu(2, 2)))
__global__ __launch_bounds__(384) void enc_scan_kernel(
    const float* __restrict__ xp,      // xp_f, with xp_b at +TLEN*BATCH*G3
    const float* Whh_f, const float* bhh_f,
    const float* Whh_b, const float* bhh_b,
    const float* __restrict__ enc_init,
    float* g)                          // [T*B, 2*EDIM]  (non-restrict: see header)
{
    const int wg  = blockIdx.x;
    const int dir = wg >> 7;
    const int b   = wg & 127;
    const int tid = threadIdx.x;
    const int lane = tid & 63;
    const float* Whh = dir ? Whh_b : Whh_f;
    const float* bhh = dir ? bhh_b : bhh_f;
    const float* __restrict__ xpd = xp + (size_t)dir * ((size_t)TLEN * BATCH * G3);

    __shared__ float h_lds[EDIM];
    __shared__ float hh_lds[G3];

    const float4* wsrc = (const float4*)(Whh + (size_t)tid * 128);
    REP32(DECLW)                       // float4 w0..w31 = this thread's Whh row

    const float brow = bhh[tid];
    if (tid < EDIM) h_lds[tid] = enc_init[dir * EDIM + tid];
    __syncthreads();

    for (int s = 0; s < TLEN; ++s) {
        const int t = dir ? (TLEN - 1 - s) : s;
        const size_t row = (size_t)t * BATCH + b;
        // prefetch xp row BEFORE the long dot (consumed after barrier A)
        float xr = 0.f, xz = 0.f, xn = 0.f;
        if (tid < EDIM) {
            const float* xrow = xpd + row * G3;
            xr = xrow[tid]; xz = xrow[EDIM + tid]; xn = xrow[2 * EDIM + tid];
        }
        // unconditional loads + unconditional dot: readlane sees all lanes live
        const int h0 = __float_as_int(h_lds[lane]);
        const int h1 = __float_as_int(h_lds[64 + lane]);
        float a0 = 0.f, a1 = 0.f, a2 = 0.f, a3 = 0.f;
        REP32(DOTW)
        hh_lds[tid] = ((a0 + a1) + (a2 + a3)) + brow;
        __syncthreads();  // A
        if (tid < EDIM) {   // waves 0,1 fully active (wave-uniform branch)
            const float hr = hh_lds[tid], hz = hh_lds[EDIM + tid], hn = hh_lds[2 * EDIM + tid];
            const float r = sigm(xr + hr);
            const float z = sigm(xz + hz);
            const float n = tanhf(xn + r * hn);
            // h_lds[tid]: wave 0 -> h0 (lane==tid), wave 1 -> h1 (64+lane==tid)
            const float hold = (tid < 64) ? __int_as_float(h0) : __int_as_float(h1);
            const float hnew = (1.f - z) * n + z * hold;
            h_lds[tid] = hnew;
            g[row * (2 * EDIM) + dir * EDIM + tid] = fminf(fmaxf(hnew, -CLIPV), CLIPV);
        }
        __syncthreads();  // B
    }
}

// ---------------------------------------------------------------------------
// Controller GRU + latent sample + spike + AR1 calcium. 128 WGs (one per batch),
// 512 threads:
//   tid 0..383  : ctrl_Whh row in w0..w31 ; tid 384..511: W_mu/W_lv row there
//   all threads : W_spk row (clamped) in s0..s16 (only waves 0..4 use it)
// Weight ptrs + out are NOT restrict (out-stores may alias -> weights must
// stay VGPR-resident); cp/eps/factors keep restrict. waves_per_eu(2,2) gives
// the 256-reg budget and removes the remat-for-occupancy incentive.
// 4 barriers/step; all readlane branches wave-uniform (verified R1-R5).
// ---------------------------------------------------------------------------
__attribute__((amdgpu_waves_per_eu(2, 2)))
__global__ __launch_bounds__(512) void ctrl_scan_kernel(
    const float* __restrict__ cp,       // [T*B, 384]
    const float* __restrict__ factors,  // [T*B, 4]
    const float* __restrict__ eps,      // [T*B, 64]
    const float* Whh, const float* bhh,
    const float* __restrict__ ctrl_init,
    const float* W_mu, const float* b_mu,
    const float* W_lv, const float* b_lv,
    const float* W_spk, const float* b_spk,
    const float* __restrict__ gain_p, const float* __restrict__ bias_p_p,
    const float* __restrict__ logtau_p,
    float* out)                         // [T*B, 300]  (non-restrict: see header)
{
    const int b   = blockIdx.x;
    const int tid = threadIdx.x;
    const int lane = tid & 63;

    __shared__ float h_lds[CDIM];
    __shared__ float hh_lds[G3];
    __shared__ float lv_lds[UDIM];
    __shared__ float gen_lds[UDIM + FDIM];

    // ---- select this thread's 128-wide weight row, then load into w0..w31 ----
    const float* wptr;
    float bias_row;
    if (tid < G3) {
        wptr = Whh + (size_t)tid * 128;
        bias_row = bhh[tid];
    } else {
        const int mrow = tid - G3;
        if (mrow < UDIM) { wptr = W_mu + (size_t)mrow * 128; bias_row = b_mu[mrow]; }
        else             { wptr = W_lv + (size_t)(mrow - UDIM) * 128; bias_row = b_lv[mrow - UDIM]; }
    }
    const float4* wsrc = (const float4*)wptr;
    REP32(DECLW)                       // float4 w0..w31

    // ---- W_spk row (clamped for pad threads; loaded by ALL threads) ----
    const int srow = (tid < NDIM) ? tid : (NDIM - 1);
    const float4* ssrc = (const float4*)(W_spk + (size_t)srow * 68);
    REP17(DECLS)                       // float4 s0..s16 (s16 = factor weights)
    const float bspk_r = b_spk[srow];

    const float gain  = gain_p[0];
    const float biasp = bias_p_p[0];
    const float decay = 1.0f - expf(-logtau_p[0]);
    if (tid < CDIM) h_lds[tid] = ctrl_init[tid];
    float cal = 0.0f;
    __syncthreads();

    int h0 = __float_as_int(h_lds[lane]);
    int h1 = __float_as_int(h_lds[64 + lane]);

    for (int t = 0; t < TLEN; ++t) {
        const size_t row = (size_t)t * BATCH + b;
        // ---- prefetch this step's global rows BEFORE the long dot ----
        float cxr = 0.f, cxz = 0.f, cxn = 0.f;   // cp row (gates, after barrier A)
        float epv = 0.f;                          // eps    (gen, after barrier C)
        float fv  = 0.f;                          // factors (LDS write, after A)
        if (tid < CDIM) {
            const float* __restrict__ cpr = cp + row * G3;
            cxr = cpr[tid]; cxz = cpr[CDIM + tid]; cxn = cpr[2 * CDIM + tid];
        }
        if (tid >= G3 && tid < G3 + UDIM) epv = eps[row * UDIM + (tid - G3)];
        if (tid >= 448 && tid < 448 + FDIM) fv = factors[row * FDIM + (tid - 448)];

        // ---- phase A: hh = Whh @ h + bhh (waves 0..5, wave-uniform) ----
        if (tid < G3) {
            float a0 = 0.f, a1 = 0.f, a2 = 0.f, a3 = 0.f;
            REP32(DOTW)
            hh_lds[tid] = ((a0 + a1) + (a2 + a3)) + bias_row;
        }
        __syncthreads();  // A
        // ---- gates (threads 0..127, waves 0,1), clip state ----
        if (tid < CDIM) {
            const float hr = hh_lds[tid], hz = hh_lds[CDIM + tid], hn = hh_lds[2 * CDIM + tid];
            const float r = sigm(cxr + hr);
            const float z = sigm(cxz + hz);
            const float n = tanhf(cxn + r * hn);
            // h_lds[tid]: wave 0 -> h0, wave 1 -> h1
            const float hold = (tid < 64) ? __int_as_float(h0) : __int_as_float(h1);
            float hnew = (1.f - z) * n + z * hold;
            hnew = fminf(fmaxf(hnew, -CLIPV), CLIPV);
            h_lds[tid] = hnew;
        }
        if (tid >= 448 && tid < 448 + FDIM) {
            gen_lds[UDIM + (tid - 448)] = fv;
        }
        __syncthreads();  // B
        h0 = __float_as_int(h_lds[lane]);        // reload new h (all lanes live)
        h1 = __float_as_int(h_lds[64 + lane]);
        // ---- phase B: mu / lv (threads 384..511, waves 6,7, wave-uniform) ----
        float muv = 0.f;
        if (tid >= G3) {
            float a0 = 0.f, a1 = 0.f, a2 = 0.f, a3 = 0.f;
            REP32(DOTW)
            const float v = ((a0 + a1) + (a2 + a3)) + bias_row;
            const int mrow = tid - G3;
            if (mrow < UDIM) muv = v; else lv_lds[mrow - UDIM] = v;
        }
        __syncthreads();  // C
        if (tid >= G3 && tid < G3 + UDIM) {
            const int j = tid - G3;
            gen_lds[j] = muv + expf(0.5f * lv_lds[j]) * epv;
        }
        __syncthreads();  // D
        // ---- phase C: spike + calcium (waves 0..4, WAVE-UNIFORM branch) ----
        if (tid < 320) {
            const int gvi = __float_as_int(gen_lds[lane]);  // all 64 lanes live
            float c0 = 0.f, c1 = 0.f, c2 = 0.f, c3 = 0.f;
            REP16(DOTS)
            float acc = (c0 + c1) + (c2 + c3);
            acc = fmaf(s16.x, gen_lds[UDIM + 0], acc);
            acc = fmaf(s16.y, gen_lds[UDIM + 1], acc);
            acc = fmaf(s16.z, gen_lds[UDIM + 2], acc);
            acc = fmaf(s16.w, gen_lds[UDIM + 3], acc);
            acc += bspk_r;
            const float sp = fmaxf(expf(acc) - 1.0f, 0.0f);
            cal = cal * decay + gain * sp + biasp;
            if (tid < NDIM) out[row * NDIM + tid] = cal;  // only the store diverges
        }
        // no barrier E: phase-C reads precede barrier A of next iter; all
        // conflicting writes next iter occur after that barrier (see R2 proof).
    }
}

// ---------------------------------------------------------------------------
extern "C" void kernel_launch(void* const* d_in, const int* in_sizes, int n_in,
                              void* d_out, int out_size, void* d_ws, size_t ws_size,
                              hipStream_t stream) {
    const float* x         = (const float*)d_in[0];
    const float* factors   = (const float*)d_in[1];
    const float* eps       = (const float*)d_in[2];
    const float* enc_Wih_f = (const float*)d_in[3];
    const float* enc_Whh_f = (const float*)d_in[4];
    const float* enc_bih_f = (const float*)d_in[5];
    const float* enc_bhh_f = (const float*)d_in[6];
    const float* enc_Wih_b = (const float*)d_in[7];
    const float* enc_Whh_b = (const float*)d_in[8];
    const float* enc_bih_b = (const float*)d_in[9];
    const float* enc_bhh_b = (const float*)d_in[10];
    const float* enc_init  = (const float*)d_in[11];
    const float* ctrl_Wih  = (const float*)d_in[12];
    const float* ctrl_Whh  = (const float*)d_in[13];
    const float* ctrl_bih  = (const float*)d_in[14];
    const float* ctrl_bhh  = (const float*)d_in[15];
    const float* ctrl_init = (const float*)d_in[16];
    const float* W_mu      = (const float*)d_in[17];
    const float* b_mu      = (const float*)d_in[18];
    const float* W_lv      = (const float*)d_in[19];
    const float* b_lv      = (const float*)d_in[20];
    const float* W_spk     = (const float*)d_in[21];
    const float* b_spk     = (const float*)d_in[22];
    const float* gain      = (const float*)d_in[23];
    const float* bias_p    = (const float*)d_in[24];
    const float* logtau    = (const float*)d_in[25];
    float* out = (float*)d_out;
    float* ws  = (float*)d_ws;

    const size_t PROJ = (size_t)TLEN * BATCH * G3;   // 24,576,000 floats
    float* xpf = ws;
    float* xpb = ws + PROJ;
    float* g   = ws + 2 * PROJ;                      // [T*B, 256]
    float* cp  = ws;                                 // reuse xpf region after encoder

    dim3 ggrid(500, 3);  // M/128 = 64000/128, N/128 = 384/128

    // xp_f = x @ enc_Wih_f.T + bih_f ; xp_b = x @ enc_Wih_b.T + bih_b
    gemm_fused_kernel<<<ggrid, 256, 0, stream>>>(x, NDIM, NDIM, 0,
                                                 nullptr, 0, 0, 0,
                                                 enc_Wih_f, NDIM, enc_bih_f, xpf, G3);
    gemm_fused_kernel<<<ggrid, 256, 0, stream>>>(x, NDIM, NDIM, 0,
                                                 nullptr, 0, 0, 0,
                                                 enc_Wih_b, NDIM, enc_bih_b, xpb, G3);
    // bidirectional encoder scans -> g (clipped)
    enc_scan_kernel<<<256, 384, 0, stream>>>(xpf, enc_Whh_f, enc_bhh_f,
                                             enc_Whh_b, enc_bhh_b, enc_init, g);
    // cp = g @ ctrl_Wih[:, :256].T + x @ ctrl_Wih[:, 256:].T + ctrl_bih
    gemm_fused_kernel<<<ggrid, 256, 0, stream>>>(g, 2 * EDIM, 2 * EDIM, 0,
                                                 x, NDIM, NDIM, 2 * EDIM,
                                                 ctrl_Wih, 2 * EDIM + NDIM, ctrl_bih, cp, G3);
    // controller scan + latent + spike + calcium -> out
    ctrl_scan_kernel<<<128, 512, 0, stream>>>(cp, factors, eps,
                                              ctrl_Whh, ctrl_bhh, ctrl_init,
                                              W_mu, b_mu, W_lv, b_lv,
                                              W_spk, b_spk,
                                              gain, bias_p, logtau, out);
}